// Round 1
// 1150.147 us; speedup vs baseline: 1.1682x; 1.1682x over previous
//
#include <hip/hip_runtime.h>
#include <math.h>

constexpr int NY_ = 320, NX_ = 320, NT_ = 160, SHOTS_ = 2, NSRC_ = 8, NREC_ = 96;
constexpr float DT_  = 4.0e-4f;
constexpr float C1_  = 9.0f / 8.0f;
constexpr float C2_  = -1.0f / 24.0f;
constexpr float IDH_ = 0.25f;           // 1/DH, exact
constexpr int NP_     = NY_ * NX_;
constexpr int NSTRIP_ = 40;             // 8-row strips per shot
constexpr int NBLK_   = SHOTS_ * NSTRIP_;
// ws layout (float words): [buf(2)][field(3: syy,sxy,sxx)][shot(2)] full grids,
// then receiver traces, then flags (one per strip-round, monotonic).
constexpr int REC_OFF_ = 12 * NP_;                          // [s][r][t] float
constexpr int FLG_OFF_ = REC_OFF_ + SHOTS_ * NREC_ * NT_;
constexpr int WS_WORDS_ = FLG_OFF_ + 128;

// ---- coherent (IF-backed) access: relaxed agent-scope atomics -> sc0 sc1,
// bypass L1/L2, served at the agent coherence point. No cache flushes needed.
__device__ __forceinline__ float cld(const float* p) {
    return __hip_atomic_load(p, __ATOMIC_RELAXED, __HIP_MEMORY_SCOPE_AGENT);
}
__device__ __forceinline__ void cst(float* p, float v) {
    __hip_atomic_store(p, v, __ATOMIC_RELAXED, __HIP_MEMORY_SCOPE_AGENT);
}
__device__ __forceinline__ unsigned cldu(const unsigned* p) {
    return __hip_atomic_load(p, __ATOMIC_RELAXED, __HIP_MEMORY_SCOPE_AGENT);
}
__device__ __forceinline__ void cstu(unsigned* p, unsigned v) {
    __hip_atomic_store(p, v, __ATOMIC_RELAXED, __HIP_MEMORY_SCOPE_AGENT);
}

// guarded halo import load: out-of-grid rows read 0 (== masked border / roll equivalence)
__device__ __forceinline__ float gldf(const float* p, int y, int c) {
    return ((unsigned)y < (unsigned)NY_) ? cld(p + y * NX_ + c) : 0.0f;
}
// guarded LDS x-tap: out-of-grid cols read 0
__device__ __forceinline__ float ltap(const float (*A)[NX_], int ly, int c) {
    return ((unsigned)c < (unsigned)NX_) ? A[ly][c] : 0.0f;
}
// register x-tap via wave shuffle: cur = this cell's column group, adj = the
// adjacent group's value in the SAME thread (cells are 64-col interleaved)
__device__ __forceinline__ float shtap(float cur, float adj, int lane, int dx) {
    int idx = (lane + dx) & 63;
    float a = __shfl(cur, idx, 64);
    float b = __shfl(adj, idx, 64);
    return ((unsigned)(lane + dx) < 64u) ? a : b;
}

// P2P neighbor sync: wave 0 polls left/right strip flags; bracketed by
// __syncthreads (the verified pattern; no __syncthreads_count).
__device__ __forceinline__ void pollNbr(const unsigned* f, int sbase, int j,
                                        unsigned tgt, int tid) {
    __syncthreads();
    if (tid < 64) {
        for (;;) {
            bool ok = true;
            if (tid == 0 && j > 0)               ok = cldu(&f[sbase + j - 1]) >= tgt;
            else if (tid == 1 && j < NSTRIP_ - 1) ok = cldu(&f[sbase + j + 1]) >= tgt;
            if (__all(ok)) break;
            __builtin_amdgcn_s_sleep(1);
        }
    }
    __syncthreads();
    asm volatile("" ::: "memory");
}

// One row's velocity + CPML update. Self stress values come from LDS (identical
// bits to the owner's registers since LDS rows are exact published copies).
__device__ __forceinline__ void vrow(
    const int lane, const int t,
    const int lyS, const int lxS, const int lv,
    float (&VY)[5], float (&VX)[5],
    float (&MSYYY)[5], float (&MSXYY)[5],
    float (&MSXYX)[5], float (&MSXXX)[5],
    const float (&SXX)[5],
    const float BY, const float BYM1,
    const float (&BX)[5], const float (&BXM1)[5],
    const float (&MK)[5], const float (&BU)[5],
    const unsigned long long SMASK,
    const float* __restrict__ ampsS,
    const float (*Lsyy)[NX_], const float (*Lsxy)[NX_],
    float (*Lvy)[NX_], float (*Lvx)[NX_])
{
    #pragma unroll
    for (int k = 0; k < 5; ++k) {
        const int c = 64 * k + lane;
        const float sxxp = (k < 4) ? SXX[k + 1] : 0.0f;
        const float sxxm = (k > 0) ? SXX[k - 1] : 0.0f;
        float d, ay, ax;
        // D-_y(syy)
        d = (C1_ * (Lsyy[lyS][c] - Lsyy[lyS - 1][c])
           + C2_ * (Lsyy[lyS + 1][c] - Lsyy[lyS - 2][c])) * IDH_;
        MSYYY[k] = BY * MSYYY[k] + BYM1 * d;
        ay = d + MSYYY[k];
        // D+_x(sxy)
        d = (C1_ * (ltap(Lsxy, lxS, c + 1) - Lsxy[lxS][c])
           + C2_ * (ltap(Lsxy, lxS, c + 2) - ltap(Lsxy, lxS, c - 1))) * IDH_;
        MSXYX[k] = BX[k] * MSXYX[k] + BXM1[k] * d;
        ay = ay + d + MSXYX[k];
        VY[k] = VY[k] + DT_ * BU[k] * ay;
        // D-_x(sxx)  (register shuffles — sxx never leaves registers)
        d = (C1_ * (SXX[k] - shtap(SXX[k], sxxm, lane, -1))
           + C2_ * (shtap(SXX[k], sxxp, lane, 1) - shtap(SXX[k], sxxm, lane, -2))) * IDH_;
        MSXXX[k] = BX[k] * MSXXX[k] + BXM1[k] * d;
        ax = d + MSXXX[k];
        // D+_y(sxy)
        d = (C1_ * (Lsxy[lxS + 1][c] - Lsxy[lxS][c])
           + C2_ * (Lsxy[lxS + 2][c] - Lsxy[lxS - 1][c])) * IDH_;
        MSXYY[k] = BY * MSXYY[k] + BYM1 * d;
        ax = ax + d + MSXYY[k];
        VX[k] = VX[k] + DT_ * BU[k] * ax;
        // source injection (interior; commutes with mask)
        unsigned m = (unsigned)(SMASK >> (8 * k)) & 0xFFu;
        if (m) {
            for (int js = 0; js < NSRC_; ++js)
                if (m & (1u << js)) VY[k] += DT_ * ampsS[js * NT_ + t] * BU[k];
        }
        VY[k] *= MK[k]; VX[k] *= MK[k];
        Lvy[lv][c] = VY[k]; Lvx[lv][c] = VX[k];
    }
}

__global__ void init_kernel(float* __restrict__ ws) {
    for (int i = blockIdx.x * 256 + threadIdx.x; i < WS_WORDS_; i += gridDim.x * 256)
        ws[i] = 0.0f;
}

__global__ __launch_bounds__(512)
void elastic_kernel(const float* __restrict__ lamb, const float* __restrict__ mu,
                    const float* __restrict__ buoy, const float* __restrict__ amps,
                    const int* __restrict__ src_loc, const int* __restrict__ rec_loc,
                    float* __restrict__ out, float* __restrict__ ws)
{
    // LDS row maps: Lvy/Lvx: gy -> gy-r0+2 (rows r0-2..r0+9)
    //               Lsyy:    gy -> gy-r0+4 (rows r0-4..r0+10)
    //               Lsxy:    gy -> gy-r0+3 (rows r0-3..r0+11)
    __shared__ float Lvy[12][NX_], Lvx[12][NX_], Lsyy[15][NX_], Lsxy[15][NX_];

    const int tid  = threadIdx.x;
    const int lane = tid & 63;
    const int w    = tid >> 6;          // local owned row 0..7 (one wave per row)
    const int bid  = blockIdx.x;
    const int s    = bid / NSTRIP_;
    const int j    = bid % NSTRIP_;
    const int r0   = j * 8;
    const int gy   = r0 + w;            // this wave's owned global row

    unsigned* flg = (unsigned*)(ws + FLG_OFF_);
    const int sbase = s * NSTRIP_;
    float* recp = ws + REC_OFF_ + (s * NREC_ + tid) * NT_;   // valid only if tid<96
    const float* ampsS = amps + s * NSRC_ * NT_;

    // --- per-cell loop invariants (k = column group, col = 64k+lane) ---
    const double d0 = 3.0 * 1600.0 * log(1000.0) / (2.0 * 20.0 * 4.0);
    double py = 0.0;
    if (gy < 20)             { double u = (20.0 - gy) / 20.0;           py = u * u; }
    else if (gy >= NY_ - 20) { double u = (gy - (NY_ - 1 - 20)) / 20.0; py = u * u; }
    const float by = (float)exp(-d0 * py * 4.0e-4);
    const float bym1 = by - 1.0f;

    float bx[5], bxm1[5], mk[5], la[5], muv[5], bu[5], l2m[5];
    #pragma unroll
    for (int k = 0; k < 5; ++k) {
        int c = 64 * k + lane;
        double px = 0.0;
        if (c < 20)             { double u = (20.0 - c) / 20.0;           px = u * u; }
        else if (c >= NX_ - 20) { double u = (c - (NX_ - 1 - 20)) / 20.0; px = u * u; }
        bx[k] = (float)exp(-d0 * px * 4.0e-4);
        bxm1[k] = bx[k] - 1.0f;
        mk[k] = (gy < 2 || gy >= NY_ - 2 || c < 2 || c >= NX_ - 2) ? 0.0f : 1.0f;
        la[k]  = lamb[gy * NX_ + c];
        muv[k] = mu[gy * NX_ + c];
        bu[k]  = buoy[gy * NX_ + c];
        l2m[k] = la[k] + 2.0f * muv[k];
    }

    // ghost-row assignment: waves 0,1 also evolve rows r0-2,r0-1; waves 6,7 rows r0+8,r0+9
    const bool isE = (w < 2) || (w >= 6);
    const int  gyE = (w < 2) ? (r0 - 2 + w) : (r0 + 2 + w);
    const bool hasE = isE && ((unsigned)gyE < (unsigned)NY_);
    const int lySE = gyE - r0 + 4, lxSE = gyE - r0 + 3, lvE = gyE - r0 + 2;

    float byE = 0.f, bym1E = 0.f, mkE[5] = {}, buE[5] = {};
    unsigned long long smE = 0ull;
    if (hasE) {
        double pyE = 0.0;
        if (gyE < 20)             { double u = (20.0 - gyE) / 20.0;           pyE = u * u; }
        else if (gyE >= NY_ - 20) { double u = (gyE - (NY_ - 1 - 20)) / 20.0; pyE = u * u; }
        byE = (float)exp(-d0 * pyE * 4.0e-4);
        bym1E = byE - 1.0f;
        #pragma unroll
        for (int k = 0; k < 5; ++k) {
            int c = 64 * k + lane;
            mkE[k] = (gyE < 2 || gyE >= NY_ - 2 || c < 2 || c >= NX_ - 2) ? 0.0f : 1.0f;
            buE[k] = buoy[gyE * NX_ + c];
        }
        for (int js = 0; js < NSRC_; ++js) {
            int sy = src_loc[(s * NSRC_ + js) * 2 + 0];
            int sx = src_loc[(s * NSRC_ + js) * 2 + 1];
            if (sy == gyE && (sx & 63) == lane) smE |= 1ull << (8 * (sx >> 6) + js);
        }
    }

    // per-thread source mask for owned row
    unsigned long long sm = 0ull;
    for (int js = 0; js < NSRC_; ++js) {
        int sy = src_loc[(s * NSRC_ + js) * 2 + 0];
        int sx = src_loc[(s * NSRC_ + js) * 2 + 1];
        if (sy == gy && (sx & 63) == lane) sm |= 1ull << (8 * (sx >> 6) + js);
    }
    // per-thread receiver (tid<96 handles receiver tid of this shot)
    bool myrec = false; int rl = 0;
    if (tid < NREC_) {
        int ry = rec_loc[(s * NREC_ + tid) * 2 + 0];
        int rx = rec_loc[(s * NREC_ + tid) * 2 + 1];
        if ((ry >> 3) == j) { myrec = true; rl = ((ry & 7) + 2) * NX_ + rx; }
    }

    // zero LDS (fields start at 0; ghost velocity rows of edge strips stay 0 forever)
    for (int i = tid; i < 15 * NX_; i += 512) {
        if (i < 12 * NX_) { ((float*)Lvy)[i] = 0.f; ((float*)Lvx)[i] = 0.f; }
        ((float*)Lsyy)[i] = 0.f; ((float*)Lsxy)[i] = 0.f;
    }

    // register state: owned rows (full) + ghost rows (velocity-phase state only)
    float vy[5] = {}, vx[5] = {}, syy[5] = {}, sxy[5] = {}, sxx[5] = {};
    float msyyy[5] = {}, msxyy[5] = {}, msxyx[5] = {}, msxxx[5] = {};
    float mvyy[5] = {}, mvyx[5] = {}, mvxy[5] = {}, mvxx[5] = {};
    float vyE[5] = {}, vxE[5] = {};
    float msyyyE[5] = {}, msxyyE[5] = {}, msxyxE[5] = {}, msxxxE[5] = {};

    for (int t = 0; t < NT_; ++t) {
        // ping-pong global stress mirrors: read buf t&1 (neighbors' round t-1
        // publish), write buf (t+1)&1. Reuse distance 2 rounds + flag gating
        // closes the read-before-overwrite race of a single-flag protocol.
        const int rb = t & 1, wb = rb ^ 1;
        const float* rSyy = ws + ((rb * 3 + 0) * SHOTS_ + s) * NP_;
        const float* rSxy = ws + ((rb * 3 + 1) * SHOTS_ + s) * NP_;
        const float* rSxx = ws + ((rb * 3 + 2) * SHOTS_ + s) * NP_;
        float* wSyy = ws + ((wb * 3 + 0) * SHOTS_ + s) * NP_;
        float* wSxy = ws + ((wb * 3 + 1) * SHOTS_ + s) * NP_;
        float* wSxx = ws + ((wb * 3 + 2) * SHOTS_ + s) * NP_;

        // ============ single exchange point per timestep ============
        pollNbr(flg, sbase, j, (unsigned)t, tid);   // neighbor stress(t-1/2) published

        if (tid < NX_) {  // import widened stress halos (batched loads, then writes)
            int c = tid;
            float a0 = gldf(rSyy, r0 - 4, c), a1 = gldf(rSyy, r0 - 3, c);
            float a2 = gldf(rSyy, r0 - 2, c), a3 = gldf(rSyy, r0 - 1, c);
            float a4 = gldf(rSyy, r0 + 8, c), a5 = gldf(rSyy, r0 + 9, c), a6 = gldf(rSyy, r0 + 10, c);
            float b0 = gldf(rSxy, r0 - 3, c), b1 = gldf(rSxy, r0 - 2, c), b2 = gldf(rSxy, r0 - 1, c);
            float b3 = gldf(rSxy, r0 + 8, c), b4 = gldf(rSxy, r0 + 9, c);
            float b5 = gldf(rSxy, r0 + 10, c), b6 = gldf(rSxy, r0 + 11, c);
            Lsyy[0][c] = a0; Lsyy[1][c] = a1; Lsyy[2][c] = a2; Lsyy[3][c] = a3;
            Lsyy[12][c] = a4; Lsyy[13][c] = a5; Lsyy[14][c] = a6;
            Lsxy[0][c] = b0; Lsxy[1][c] = b1; Lsxy[2][c] = b2;
            Lsxy[11][c] = b3; Lsxy[12][c] = b4; Lsxy[13][c] = b5; Lsxy[14][c] = b6;
        }
        float sxxE[5];
        if (hasE) {   // ghost-row sxx (x-derivative only -> straight into registers)
            #pragma unroll
            for (int k = 0; k < 5; ++k) sxxE[k] = cld(rSxx + gyE * NX_ + 64 * k + lane);
        }
        __syncthreads();

        // ============ velocity: 8 owned rows + up to 2 ghost rows/side ============
        vrow(lane, t, w + 4, w + 3, w + 2,
             vy, vx, msyyy, msxyy, msxyx, msxxx, sxx,
             by, bym1, bx, bxm1, mk, bu, sm, ampsS, Lsyy, Lsxy, Lvy, Lvx);
        if (hasE)
            vrow(lane, t, lySE, lxSE, lvE,
                 vyE, vxE, msyyyE, msxyyE, msxyxE, msxxxE, sxxE,
                 byE, bym1E, bx, bxm1, mkE, buE, smE, ampsS, Lsyy, Lsxy, Lvy, Lvx);
        __syncthreads();

        // record receivers (strip-local)
        if (myrec) recp[t] = ((const float*)Lvy)[rl];

        // ============ stress: owned rows only (all velocity rows local) ============
        {
            const int lv = w + 2;
            #pragma unroll
            for (int k = 0; k < 5; ++k) {
                const int c = 64 * k + lane;
                float d, e1, e2, g;
                // D+_y(vy)
                d = (C1_ * (Lvy[lv + 1][c] - vy[k]) + C2_ * (Lvy[lv + 2][c] - Lvy[lv - 1][c])) * IDH_;
                mvyy[k] = by * mvyy[k] + bym1 * d;
                e1 = d + mvyy[k];
                // D-_x(vx)
                d = (C1_ * (vx[k] - ltap(Lvx, lv, c - 1))
                   + C2_ * (ltap(Lvx, lv, c + 1) - ltap(Lvx, lv, c - 2))) * IDH_;
                mvxx[k] = bx[k] * mvxx[k] + bxm1[k] * d;
                e2 = d + mvxx[k];
                syy[k] = (syy[k] + DT_ * (l2m[k] * e1 + la[k] * e2)) * mk[k];
                sxx[k] = (sxx[k] + DT_ * (l2m[k] * e2 + la[k] * e1)) * mk[k];
                // D+_x(vy)
                d = (C1_ * (ltap(Lvy, lv, c + 1) - vy[k])
                   + C2_ * (ltap(Lvy, lv, c + 2) - ltap(Lvy, lv, c - 1))) * IDH_;
                mvyx[k] = bx[k] * mvyx[k] + bxm1[k] * d;
                g = d + mvyx[k];
                // D-_y(vx)
                d = (C1_ * (vx[k] - Lvx[lv - 1][c]) + C2_ * (Lvx[lv + 1][c] - Lvx[lv - 2][c])) * IDH_;
                mvxy[k] = by * mvxy[k] + bym1 * d;
                g = g + d + mvxy[k];
                sxy[k] = (sxy[k] + DT_ * muv[k] * g) * mk[k];
                Lsyy[w + 4][c] = syy[k];
                Lsxy[w + 3][c] = sxy[k];
                // publish halo rows straight from registers (per-wave, coalesced):
                // syy rows {0,1,2,4,5,6,7}, sxy rows {0,1,2,3,5,6,7}, sxx rows {0,1,6,7}
                if (w != 3) cst(&wSyy[gy * NX_ + c], syy[k]);
                if (w != 4) cst(&wSxy[gy * NX_ + c], sxy[k]);
                if (isE)    cst(&wSxx[gy * NX_ + c], sxx[k]);
            }
        }
        __syncthreads();   // compiler drains each wave's vmcnt before s_barrier
        if (tid == 0) {
            asm volatile("s_waitcnt vmcnt(0)" ::: "memory");
            cstu(&flg[sbase + j], (unsigned)(t + 1));
        }
    }

    // ---------- final output: out[s][r][t] = 0.5*(rec[t] + rec[t+1]) ----------
    if (myrec) {
        float* op = out + (s * NREC_ + tid) * (NT_ - 1);
        for (int t = 0; t < NT_ - 1; ++t) op[t] = 0.5f * (recp[t] + recp[t + 1]);
    }
}

extern "C" void kernel_launch(void* const* d_in, const int* in_sizes, int n_in,
                              void* d_out, int out_size, void* d_ws, size_t ws_size,
                              hipStream_t stream)
{
    const float* lamb = (const float*)d_in[0];
    const float* mu   = (const float*)d_in[1];
    const float* buoy = (const float*)d_in[2];
    const float* amps = (const float*)d_in[3];
    const int*   src  = (const int*)d_in[4];
    const int*   recl = (const int*)d_in[5];
    float* out = (float*)d_out;
    float* ws  = (float*)d_ws;

    init_kernel<<<dim3(512), dim3(256), 0, stream>>>(ws);
    elastic_kernel<<<dim3(NBLK_), dim3(512), 0, stream>>>(lamb, mu, buoy, amps, src, recl, out, ws);
}